// Round 9
// baseline (432.047 us; speedup 1.0000x reference)
//
#include <hip/hip_runtime.h>
#include <cstddef>

typedef short  bf16x8 __attribute__((ext_vector_type(8)));
typedef float  f32x16 __attribute__((ext_vector_type(16)));

#define IC 2048
#define JD 16
#define NC 64
#define DD 32
#define ICH 8                  // i per accum block
#define NPG (IC / ICH)         // 256 sPart pages

// ---------------------------------------------------------------- helpers ---
__device__ __forceinline__ unsigned f2bf1(float f) {          // RNE f32->bf16
  unsigned u = __float_as_uint(f);
  return (u + 0x7FFFu + ((u >> 16) & 1u)) >> 16;
}
__device__ __forceinline__ unsigned pk2(float lo, float hi) { // 2 bf16 in u32
  return f2bf1(lo) | (f2bf1(hi) << 16);
}
__device__ __forceinline__ float bflo(unsigned v) { return __uint_as_float(v << 16); }
__device__ __forceinline__ float bfhi(unsigned v) { return __uint_as_float(v & 0xFFFF0000u); }

template<int CTRL>
__device__ __forceinline__ float dpp_mov_f(float v) {
  int x = __builtin_amdgcn_mov_dpp(__float_as_int(v), CTRL, 0xf, 0xf, true);
  return __int_as_float(x);
}
__device__ __forceinline__ float row16_sum(float v) {
  v += dpp_mov_f<0x121>(v);
  v += dpp_mov_f<0x122>(v);
  v += dpp_mov_f<0x124>(v);
  v += dpp_mov_f<0x128>(v);
  return v;
}

// ========================================================= MFMA path ========

// accum r0: c = 1/64 exactly. Also converts W f32 -> Wb bf16 (each element
// owned by exactly one wave). Depth-1 register prefetch of next il's W.
__global__ __launch_bounds__(256, 5) void caps_accum0(
    const float* __restrict__ x, const float* __restrict__ Wf,
    unsigned short* __restrict__ Wb, float* __restrict__ sPart)
{
  const int t = threadIdx.x, w = t >> 6, l = t & 63;
  const int m = l & 31, h = l >> 5;
  const int ic = blockIdx.x >> 3, nq = blockIdx.x & 7;
  const int i0 = ic * ICH;
  const int n0 = nq * 8 + w * 2;
  __shared__ __align__(16) unsigned short xl[ICH][32][16];   // 8 KB
  for (int g = t; g < ICH * 128; g += 256) {
    int il = g >> 7, bb = (g >> 2) & 31, q4 = g & 3;
    const float4 xv = *reinterpret_cast<const float4*>(
        x + ((size_t)bb * IC + (i0 + il)) * JD + q4 * 4);
    unsigned* dst = reinterpret_cast<unsigned*>(&xl[il][bb][q4 * 4]);
    dst[0] = pk2(xv.x, xv.y);
    dst[1] = pk2(xv.z, xv.w);
  }
  __syncthreads();
  f32x16 sacc0 = (f32x16)0.0f, sacc1 = (f32x16)0.0f;

  const size_t base0 = (((size_t)n0 * IC + i0) * DD + m) * JD + h * 8;
  const size_t base1 = ((((size_t)n0 + 1) * IC + i0) * DD + m) * JD + h * 8;
  // il stride = DD*JD = 512 elements
  float4 A0 = *reinterpret_cast<const float4*>(Wf + base0);
  float4 A1 = *reinterpret_cast<const float4*>(Wf + base0 + 4);
  float4 B0 = *reinterpret_cast<const float4*>(Wf + base1);
  float4 B1 = *reinterpret_cast<const float4*>(Wf + base1 + 4);
#pragma unroll
  for (int p2 = 0; p2 < ICH / 2; ++p2) {
    const int ilA = 2 * p2, ilB = 2 * p2 + 1;
    // prefetch ilB while ilA is processed
    float4 C0 = *reinterpret_cast<const float4*>(Wf + base0 + (size_t)ilB * 512);
    float4 C1 = *reinterpret_cast<const float4*>(Wf + base0 + (size_t)ilB * 512 + 4);
    float4 D0 = *reinterpret_cast<const float4*>(Wf + base1 + (size_t)ilB * 512);
    float4 D1 = *reinterpret_cast<const float4*>(Wf + base1 + (size_t)ilB * 512 + 4);
    {
      uint4 pA, pB;
      pA.x = pk2(A0.x, A0.y); pA.y = pk2(A0.z, A0.w);
      pA.z = pk2(A1.x, A1.y); pA.w = pk2(A1.z, A1.w);
      pB.x = pk2(B0.x, B0.y); pB.y = pk2(B0.z, B0.w);
      pB.z = pk2(B1.x, B1.y); pB.w = pk2(B1.z, B1.w);
      *reinterpret_cast<uint4*>(Wb + base0 + (size_t)ilA * 512) = pA;
      *reinterpret_cast<uint4*>(Wb + base1 + (size_t)ilA * 512) = pB;
      bf16x8 bfrag = *reinterpret_cast<const bf16x8*>(&xl[ilA][m][h * 8]);
      sacc0 = __builtin_amdgcn_mfma_f32_32x32x16_bf16(
          *reinterpret_cast<bf16x8*>(&pA), bfrag, sacc0, 0, 0, 0);
      sacc1 = __builtin_amdgcn_mfma_f32_32x32x16_bf16(
          *reinterpret_cast<bf16x8*>(&pB), bfrag, sacc1, 0, 0, 0);
    }
    if (p2 + 1 < ICH / 2) {   // prefetch next pair's first il
      const int ilN = ilA + 2;
      A0 = *reinterpret_cast<const float4*>(Wf + base0 + (size_t)ilN * 512);
      A1 = *reinterpret_cast<const float4*>(Wf + base0 + (size_t)ilN * 512 + 4);
      B0 = *reinterpret_cast<const float4*>(Wf + base1 + (size_t)ilN * 512);
      B1 = *reinterpret_cast<const float4*>(Wf + base1 + (size_t)ilN * 512 + 4);
    }
    {
      uint4 pA, pB;
      pA.x = pk2(C0.x, C0.y); pA.y = pk2(C0.z, C0.w);
      pA.z = pk2(C1.x, C1.y); pA.w = pk2(C1.z, C1.w);
      pB.x = pk2(D0.x, D0.y); pB.y = pk2(D0.z, D0.w);
      pB.z = pk2(D1.x, D1.y); pB.w = pk2(D1.z, D1.w);
      *reinterpret_cast<uint4*>(Wb + base0 + (size_t)ilB * 512) = pA;
      *reinterpret_cast<uint4*>(Wb + base1 + (size_t)ilB * 512) = pB;
      bf16x8 bfrag = *reinterpret_cast<const bf16x8*>(&xl[ilB][m][h * 8]);
      sacc0 = __builtin_amdgcn_mfma_f32_32x32x16_bf16(
          *reinterpret_cast<bf16x8*>(&pA), bfrag, sacc0, 0, 0, 0);
      sacc1 = __builtin_amdgcn_mfma_f32_32x32x16_bf16(
          *reinterpret_cast<bf16x8*>(&pB), bfrag, sacc1, 0, 0, 0);
    }
  }
  float* page = sPart + (size_t)ic * 65536;      // [n][dchunk][b][4]
#pragma unroll
  for (int q = 0; q < 4; ++q) {
    float4 v0 = make_float4(sacc0[4*q]*0.015625f, sacc0[4*q+1]*0.015625f,
                            sacc0[4*q+2]*0.015625f, sacc0[4*q+3]*0.015625f);
    float4 v1 = make_float4(sacc1[4*q]*0.015625f, sacc1[4*q+1]*0.015625f,
                            sacc1[4*q+2]*0.015625f, sacc1[4*q+3]*0.015625f);
    *reinterpret_cast<float4*>(page + (((size_t)n0*8 + 2*q+h)*32 + m)*4) = v0;
    *reinterpret_cast<float4*>(page + ((((size_t)n0+1)*8 + 2*q+h)*32 + m)*4) = v1;
  }
}

// logits (r>=1): per i, all 64 n; writes C[i][n][b] = e/den. afrag prefetch.
__global__ __launch_bounds__(256, 6) void caps_logits(
    const float* __restrict__ x, const unsigned short* __restrict__ Wb,
    const unsigned short* __restrict__ Vb, float* __restrict__ C)
{
  const int t = threadIdx.x, w = t >> 6, l = t & 63;
  const int m = l & 31, h = l >> 5;
  const int i = blockIdx.x;                      // grid 2048
  __shared__ __align__(16) unsigned short xl[32][16];
  __shared__ float den4[4][32];
  __shared__ float denf[32];
  if (t < 128) {
    int bb = t >> 2, q4 = t & 3;
    const float4 xv = *reinterpret_cast<const float4*>(
        x + ((size_t)bb * IC + i) * JD + q4 * 4);
    unsigned* dst = reinterpret_cast<unsigned*>(&xl[bb][q4 * 4]);
    dst[0] = pk2(xv.x, xv.y);
    dst[1] = pk2(xv.z, xv.w);
  }
  __syncthreads();
  bf16x8 bfrag = *reinterpret_cast<const bf16x8*>(&xl[m][h * 8]);
  const size_t wbase = (((size_t)(w * 16) * IC + i) * DD + m) * JD + h * 8;
  // nn stride in Wb = IC*DD*JD elements
  const size_t nstride = (size_t)IC * DD * JD;
  float e[16];
  float pden = 0.f;
  bf16x8 af = *reinterpret_cast<const bf16x8*>(Wb + wbase);
#pragma unroll
  for (int nn = 0; nn < 16; ++nn) {
    bf16x8 nx;
    if (nn < 15)
      nx = *reinterpret_cast<const bf16x8*>(Wb + wbase + (size_t)(nn + 1) * nstride);
    const int n = w * 16 + nn;
    f32x16 u = __builtin_amdgcn_mfma_f32_32x32x16_bf16(
        af, bfrag, (f32x16)0.0f, 0, 0, 0);
    float partial = 0.f;
    const unsigned short* vrow = Vb + ((size_t)m * NC + n) * DD;
#pragma unroll
    for (int q = 0; q < 4; ++q) {                // d-chunk 2q+h
      uint2 vv = *reinterpret_cast<const uint2*>(vrow + (2 * q + h) * 4);
      partial += bflo(vv.x) * u[4*q+0] + bfhi(vv.x) * u[4*q+1]
               + bflo(vv.y) * u[4*q+2] + bfhi(vv.y) * u[4*q+3];
    }
    float logit = partial + __shfl_xor(partial, 32);
    // |logit| small (V squashed): exp safe w/o max-sub; shift-invariant.
    e[nn] = __expf(logit);
    pden += e[nn];
    af = nx;
  }
  if (h == 0) den4[w][m] = pden;
  __syncthreads();
  if (t < 32) denf[t] = 1.0f / (den4[0][t] + den4[1][t] + den4[2][t] + den4[3][t]);
  __syncthreads();
  if (h == 0) {
    float rden = denf[m];
    float* crow = C + ((size_t)i * NC + w * 16) * 32 + m;
#pragma unroll
    for (int nn = 0; nn < 16; ++nn) crow[nn * 32] = e[nn] * rden;
  }
}

// accum r1/r2: weighted GEMM, c from C. Depth-1 prefetch of afrags + c.
__global__ __launch_bounds__(256, 5) void caps_accum12(
    const float* __restrict__ x, const unsigned short* __restrict__ Wb,
    const float* __restrict__ C, float* __restrict__ sPart)
{
  const int t = threadIdx.x, w = t >> 6, l = t & 63;
  const int m = l & 31, h = l >> 5;
  const int ic = blockIdx.x >> 3, nq = blockIdx.x & 7;
  const int i0 = ic * ICH;
  const int n0 = nq * 8 + w * 2;
  __shared__ __align__(16) unsigned short xl[ICH][32][16];   // 8 KB
  for (int g = t; g < ICH * 128; g += 256) {
    int il = g >> 7, bb = (g >> 2) & 31, q4 = g & 3;
    const float4 xv = *reinterpret_cast<const float4*>(
        x + ((size_t)bb * IC + (i0 + il)) * JD + q4 * 4);
    unsigned* dst = reinterpret_cast<unsigned*>(&xl[il][bb][q4 * 4]);
    dst[0] = pk2(xv.x, xv.y);
    dst[1] = pk2(xv.z, xv.w);
  }
  __syncthreads();
  f32x16 sacc0 = (f32x16)0.0f, sacc1 = (f32x16)0.0f;
  const size_t base0 = (((size_t)n0 * IC + i0) * DD + m) * JD + h * 8;
  const size_t base1 = ((((size_t)n0 + 1) * IC + i0) * DD + m) * JD + h * 8;
  bf16x8 af0 = *reinterpret_cast<const bf16x8*>(Wb + base0);
  bf16x8 af1 = *reinterpret_cast<const bf16x8*>(Wb + base1);
  float c0 = C[((size_t)i0 * NC + n0) * 32 + m];
  float c1 = C[((size_t)i0 * NC + n0 + 1) * 32 + m];
#pragma unroll
  for (int il = 0; il < ICH; ++il) {
    bf16x8 nf0, nf1; float nc0 = 0.f, nc1 = 0.f;
    if (il + 1 < ICH) {
      nf0 = *reinterpret_cast<const bf16x8*>(Wb + base0 + (size_t)(il + 1) * 512);
      nf1 = *reinterpret_cast<const bf16x8*>(Wb + base1 + (size_t)(il + 1) * 512);
      nc0 = C[((size_t)(i0 + il + 1) * NC + n0) * 32 + m];
      nc1 = C[((size_t)(i0 + il + 1) * NC + n0 + 1) * 32 + m];
    }
    bf16x8 bfrag = *reinterpret_cast<const bf16x8*>(&xl[il][m][h * 8]);
    f32x16 u0 = __builtin_amdgcn_mfma_f32_32x32x16_bf16(
        af0, bfrag, (f32x16)0.0f, 0, 0, 0);
    f32x16 u1 = __builtin_amdgcn_mfma_f32_32x32x16_bf16(
        af1, bfrag, (f32x16)0.0f, 0, 0, 0);
#pragma unroll
    for (int k = 0; k < 16; ++k) {
      sacc0[k] += c0 * u0[k];
      sacc1[k] += c1 * u1[k];
    }
    af0 = nf0; af1 = nf1; c0 = nc0; c1 = nc1;
  }
  float* page = sPart + (size_t)ic * 65536;
#pragma unroll
  for (int q = 0; q < 4; ++q) {
    float4 v0 = make_float4(sacc0[4*q], sacc0[4*q+1], sacc0[4*q+2], sacc0[4*q+3]);
    float4 v1 = make_float4(sacc1[4*q], sacc1[4*q+1], sacc1[4*q+2], sacc1[4*q+3]);
    *reinterpret_cast<float4*>(page + (((size_t)n0*8 + 2*q+h)*32 + m)*4) = v0;
    *reinterpret_cast<float4*>(page + ((((size_t)n0+1)*8 + 2*q+h)*32 + m)*4) = v1;
  }
}

// reduce level 1: 256 pages -> 8 partial pages
__global__ __launch_bounds__(256) void caps_reduce1(
    const float4* __restrict__ sPart, float4* __restrict__ part2) {
  int blk = blockIdx.x;              // 512 = 8 pg x 64 fb
  int pg = blk >> 6, fb = blk & 63;
  int fid = fb * 256 + threadIdx.x;  // 0..16383
  float4 a = make_float4(0.f, 0.f, 0.f, 0.f);
#pragma unroll 8
  for (int p = 0; p < 32; ++p) {
    float4 v = sPart[(size_t)(pg * 32 + p) * 16384 + fid];
    a.x += v.x; a.y += v.y; a.z += v.z; a.w += v.w;
  }
  part2[(size_t)pg * 16384 + fid] = a;
}

// fused reduce level 2 + squash. grid 64 (one n per block), 256 thr:
// t = dc*32 + b. Sums 8 part2 pages, LDS-reduces s2 over dc, applies squash,
// writes V+Vb (mode 0/1) or out (mode 2).
__global__ __launch_bounds__(256) void caps_redsq(
    const float4* __restrict__ part2, float* __restrict__ V,
    unsigned short* __restrict__ Vb, float* __restrict__ out, int mode)
{
  const int n = blockIdx.x, t = threadIdx.x;
  const int dc = t >> 5, b = t & 31;
  const int fid = n * 256 + t;
  __shared__ float sq[8][32];
  float4 a = make_float4(0.f, 0.f, 0.f, 0.f);
#pragma unroll
  for (int pg = 0; pg < 8; ++pg) {
    float4 v = part2[(size_t)pg * 16384 + fid];
    a.x += v.x; a.y += v.y; a.z += v.z; a.w += v.w;
  }
  sq[dc][b] = a.x*a.x + a.y*a.y + a.z*a.z + a.w*a.w;
  __syncthreads();
  float s2 = 0.f;
#pragma unroll
  for (int q = 0; q < 8; ++q) s2 += sq[q][b];
  float scale = s2 / ((1.0f + s2) * sqrtf(s2 + 1e-7f));
  float4 vd = make_float4(a.x*scale, a.y*scale, a.z*scale, a.w*scale);
  const size_t off = ((size_t)b * NC + n) * DD + dc * 4;
  if (mode == 2) {
    *reinterpret_cast<float4*>(out + off) = vd;
  } else {
    float4 nv = vd;
    if (mode == 1) {
      float4 old = *reinterpret_cast<const float4*>(V + off);
      nv.x += old.x; nv.y += old.y; nv.z += old.z; nv.w += old.w;
    }
    *reinterpret_cast<float4*>(V + off) = nv;
    uint2 pb;
    pb.x = pk2(nv.x, nv.y);
    pb.y = pk2(nv.z, nv.w);
    *reinterpret_cast<uint2*>(Vb + off) = pb;
  }
}

// ============================== fallback: R6 f32 path (ws too small) ========
__global__ void fb_zero(float* __restrict__ s) {
  s[blockIdx.x * 256 + threadIdx.x] = 0.0f;
}
__global__ __launch_bounds__(1024, 4)
void fb_pass(const float* __restrict__ x, const float* __restrict__ W,
             const float* __restrict__ V, float* __restrict__ sOut,
             float* __restrict__ sPart, int r, int usePart)
{
  const int t = threadIdx.x, w = t >> 6, l = t & 63;
  const int n = (w << 2) | (l >> 4);
  const int d0 = (l & 15) << 1;
  const int blk = blockIdx.x, xcd = blk & 7, slot = blk >> 3;
  const int ic = xcd * 8 + (slot >> 3), bq = slot & 7;
  const int i0 = ic * 32, bbase = bq * 4;
  __shared__ float den[2][4];
  __shared__ float Vlds[4 * NC * DD];
  if (r != 0) {
    const float4* src = reinterpret_cast<const float4*>(V + (size_t)bbase * 2048);
    float4* dst = reinterpret_cast<float4*>(Vlds);
    dst[t] = src[t]; dst[t + 1024] = src[t + 1024];
  }
  float acc0[4], acc1[4];
#pragma unroll
  for (int b = 0; b < 4; ++b) { acc0[b] = 0.f; acc1[b] = 0.f; }
  for (int ii = 0; ii < 32; ++ii) {
    const int i = i0 + ii, p = ii & 1;
    const float4* Wp = reinterpret_cast<const float4*>(
        W + (((size_t)n * IC + i) * DD + d0) * JD);
    float4 wr[8];
#pragma unroll
    for (int q = 0; q < 8; ++q) wr[q] = Wp[q];
    if (r == 0) {
#pragma unroll
      for (int bb = 0; bb < 4; ++bb) {
        const float* xp = x + ((size_t)(bbase + bb) * IC + i) * JD;
        float u0 = 0.f, u1 = 0.f;
#pragma unroll
        for (int q = 0; q < 4; ++q) {
          float4 w0 = wr[q], w1 = wr[4 + q];
          float x0 = xp[4*q], x1 = xp[4*q+1], x2 = xp[4*q+2], x3 = xp[4*q+3];
          u0 += w0.x*x0 + w0.y*x1 + w0.z*x2 + w0.w*x3;
          u1 += w1.x*x0 + w1.y*x1 + w1.z*x2 + w1.w*x3;
        }
        acc0[bb] += u0 * 0.015625f; acc1[bb] += u1 * 0.015625f;
      }
    } else {
      if (t < 4) den[p][t] = 0.0f;
      __syncthreads();
      float p0a[4], p1a[4];
#pragma unroll
      for (int bb = 0; bb < 4; ++bb) {
        const float* xp = x + ((size_t)(bbase + bb) * IC + i) * JD;
        float u0 = 0.f, u1 = 0.f;
#pragma unroll
        for (int q = 0; q < 4; ++q) {
          float4 w0 = wr[q], w1 = wr[4 + q];
          float x0 = xp[4*q], x1 = xp[4*q+1], x2 = xp[4*q+2], x3 = xp[4*q+3];
          u0 += w0.x*x0 + w0.y*x1 + w0.z*x2 + w0.w*x3;
          u1 += w1.x*x0 + w1.y*x1 + w1.z*x2 + w1.w*x3;
        }
        const float2 vv = *reinterpret_cast<const float2*>(
            &Vlds[((size_t)bb * NC + n) * DD + d0]);
        float lp = u0 * vv.x + u1 * vv.y;
        float logit = row16_sum(lp);
        float e = __expf(logit);
        p0a[bb] = e * u0; p1a[bb] = e * u1;
        float es = e + __shfl_xor(e, 16);
        es += __shfl_xor(es, 32);
        if (l == 0) atomicAdd(&den[p][bb], es);
      }
      __syncthreads();
#pragma unroll
      for (int bb = 0; bb < 4; ++bb) {
        float rd = 1.0f / den[p][bb];
        acc0[bb] += p0a[bb] * rd; acc1[bb] += p1a[bb] * rd;
      }
    }
  }
  if (usePart) {
#pragma unroll
    for (int bb = 0; bb < 4; ++bb) {
      float2 v2 = make_float2(acc0[bb], acc1[bb]);
      size_t off = (((size_t)(bq * 64 + ic) * 4 + bb) * NC + n) * DD + d0;
      *reinterpret_cast<float2*>(sPart + off) = v2;
    }
  } else {
#pragma unroll
    for (int bb = 0; bb < 4; ++bb) {
      float* sp = sOut + ((size_t)(bbase + bb) * NC + n) * DD + d0;
      atomicAdd(sp, acc0[bb]); atomicAdd(sp + 1, acc1[bb]);
    }
  }
}
__global__ void fb_reduceS(const float4* __restrict__ sPart, float4* __restrict__ s) {
  int q = blockIdx.x * 256 + threadIdx.x;
  int bq = q >> 11, qq = q & 2047;
  float4 sum = make_float4(0.f, 0.f, 0.f, 0.f);
#pragma unroll 8
  for (int p = 0; p < 64; ++p) {
    float4 v = sPart[(size_t)(bq * 64 + p) * 2048 + qq];
    sum.x += v.x; sum.y += v.y; sum.z += v.z; sum.w += v.w;
  }
  s[q] = sum;
}
__global__ void fb_squash(const float* __restrict__ s, float* __restrict__ V,
                          float* __restrict__ out, int mode)
{
  const int t = threadIdx.x;
  const int g = blockIdx.x * 8 + (t >> 5);
  const int d = t & 31;
  float v = s[(size_t)g * DD + d];
  float s2 = v * v;
#pragma unroll
  for (int off = 16; off; off >>= 1) s2 += __shfl_xor(s2, off);
  float scale = s2 / ((1.0f + s2) * sqrtf(s2 + 1e-7f));
  float vd = scale * v;
  if (mode == 2)      out[(size_t)g * DD + d] = vd;
  else if (mode == 0) V[(size_t)g * DD + d] = vd;
  else                V[(size_t)g * DD + d] += vd;
}

// ---------------------------------------------------------------------------
extern "C" void kernel_launch(void* const* d_in, const int* in_sizes, int n_in,
                              void* d_out, int out_size, void* d_ws, size_t ws_size,
                              hipStream_t stream) {
  const float* x = (const float*)d_in[0];
  const float* W = (const float*)d_in[1];
  float* out = (float*)d_out;
  char* ws = (char*)d_ws;
  // Wb 134217728 | sPart 67108864 | C 16777216 | part2 2097152 | V 262144
  // Vb 131072  => total 220594176
  const size_t NEED_NEW = 220594176ull;

  if (ws_size >= NEED_NEW) {
    unsigned short* Wb = (unsigned short*)ws;
    float* sPart = (float*)(ws + 134217728);
    float* Cbuf  = (float*)(ws + 201326592);
    float* part2 = (float*)(ws + 218103808);
    float* V     = (float*)(ws + 220200960);
    unsigned short* Vb = (unsigned short*)(ws + 220463104);
    for (int r = 0; r < 3; ++r) {
      if (r == 0) {
        caps_accum0<<<2048, 256, 0, stream>>>(x, W, Wb, sPart);
      } else {
        caps_logits<<<2048, 256, 0, stream>>>(x, Wb, Vb, Cbuf);
        caps_accum12<<<2048, 256, 0, stream>>>(x, Wb, Cbuf, sPart);
      }
      caps_reduce1<<<512, 256, 0, stream>>>((const float4*)sPart, (float4*)part2);
      caps_redsq<<<64, 256, 0, stream>>>((const float4*)part2, V, Vb, out,
                                         r == 2 ? 2 : (r == 0 ? 0 : 1));
    }
  } else {
    float* s     = (float*)ws;
    float* V     = s + 65536;
    float* sPart = V + 65536;
    const size_t need1 = (2ull * 65536 + 512ull * 8192) * 4;
    const int usePart = (ws_size >= need1) ? 1 : 0;
    for (int r = 0; r < 3; ++r) {
      if (!usePart) fb_zero<<<256, 256, 0, stream>>>(s);
      fb_pass<<<512, 1024, 0, stream>>>(x, W, V, s, sPart, r, usePart);
      if (usePart)
        fb_reduceS<<<64, 256, 0, stream>>>((const float4*)sPart, (float4*)s);
      fb_squash<<<256, 256, 0, stream>>>(s, V, out, r == 2 ? 2 : (r == 0 ? 0 : 1));
    }
  }
}